// Round 4
// baseline (81.269 us; speedup 1.0000x reference)
//
#include <hip/hip_runtime.h>
#include <math.h>

typedef __attribute__((ext_vector_type(8))) short bf16x8;
typedef __attribute__((ext_vector_type(4))) short bf16x4;
typedef __attribute__((ext_vector_type(4))) float f32x4;

__device__ inline ushort f2bf(float f) {
    union { float f; uint u; } v; v.f = f;
    uint u = v.u;
    return (ushort)((u + 0x7fff + ((u >> 16) & 1)) >> 16);   // RNE
}
__device__ inline float bf2f(ushort u) {
    union { uint u; float f; } v; v.u = ((uint)u) << 16; return v.f;
}

// ---------------------------------------------------------------------------
// MFMA bf16 GEMM, converts inputs on the fly.
//   A: MODE0 = f32 row-major (lda=K), MODE1 = bf16 row-major (lda=K)
//   B: f32 row-major (K x N, ldb), transposed+converted into LDS
//   out: MODE0 = bf16 split into 3 buffers of 256 cols (q,k,v); MODE1 = f32
// LDS 16B-chunk XOR swizzle: chunk g of row r stored at g ^ ((r>>1)&3)  (2-way max)
// ---------------------------------------------------------------------------
template<int BM, int BN, int WGM, int WGN, int MODE>
__global__ __launch_bounds__(WGM * WGN * 64) void gemm_fused(
    const void* __restrict__ Ap, const float* __restrict__ Bw, int ldb,
    const float* __restrict__ bias,
    void* __restrict__ C0, void* __restrict__ C1, void* __restrict__ C2,
    int K, int N)
{
    constexpr int BK = 32;
    constexpr int NT = WGM * WGN * 64;
    constexpr int WM = BM / (WGM * 16);
    constexpr int WN = BN / (WGN * 16);

    __shared__ ushort As[BM * BK];
    __shared__ ushort Bs[BN * BK];

    const int tid = threadIdx.x;
    const int lane = tid & 63, wid = tid >> 6;
    const int wm = wid / WGN, wn = wid % WGN;
    const int row0 = blockIdx.y * BM, col0 = blockIdx.x * BN;
    const int frow = lane & 15, fg = lane >> 4;

    f32x4 acc[WM][WN] = {};

    for (int k0 = 0; k0 < K; k0 += BK) {
        if constexpr (MODE == 0) {
            #pragma unroll
            for (int ci = tid; ci < BM * 8; ci += NT) {
                int r = ci >> 3, kq = ci & 7, g = kq >> 1;
                float4 v = *(const float4*)((const float*)Ap + (size_t)(row0 + r) * K + k0 + kq * 4);
                bf16x4 o;
                o[0] = (short)f2bf(v.x); o[1] = (short)f2bf(v.y);
                o[2] = (short)f2bf(v.z); o[3] = (short)f2bf(v.w);
                *(bf16x4*)&As[r * 32 + ((g ^ ((r >> 1) & 3)) << 3) + (kq & 1) * 4] = o;
            }
        } else {
            #pragma unroll
            for (int ci = tid; ci < BM * 4; ci += NT) {
                int r = ci >> 2, g = ci & 3;
                bf16x8 v = *(const bf16x8*)((const ushort*)Ap + (size_t)(row0 + r) * K + k0 + g * 8);
                *(bf16x8*)&As[r * 32 + ((g ^ ((r >> 1) & 3)) << 3)] = v;
            }
        }
        // B: read f32 (k-row, n-cols) and transpose into Bs[n][k]
        #pragma unroll
        for (int ci = tid; ci < BN * 8; ci += NT) {
            int kk = ci & 31, n4 = ci >> 5;
            float4 v = *(const float4*)&Bw[(size_t)(k0 + kk) * ldb + col0 + n4 * 4];
            float vv[4] = {v.x, v.y, v.z, v.w};
            #pragma unroll
            for (int e = 0; e < 4; ++e) {
                int n = n4 * 4 + e;
                Bs[n * 32 + (((kk >> 3) ^ ((n >> 1) & 3)) << 3) + (kk & 7)] = f2bf(vv[e]);
            }
        }
        __syncthreads();

        bf16x8 af[WM], bfr[WN];
        #pragma unroll
        for (int m = 0; m < WM; ++m) {
            int r = (wm * WM + m) * 16 + frow;
            af[m] = *(const bf16x8*)&As[r * 32 + ((fg ^ ((r >> 1) & 3)) << 3)];
        }
        #pragma unroll
        for (int n = 0; n < WN; ++n) {
            int r = (wn * WN + n) * 16 + frow;
            bfr[n] = *(const bf16x8*)&Bs[r * 32 + ((fg ^ ((r >> 1) & 3)) << 3)];
        }
        #pragma unroll
        for (int m = 0; m < WM; ++m)
            #pragma unroll
            for (int n = 0; n < WN; ++n)
                acc[m][n] = __builtin_amdgcn_mfma_f32_16x16x32_bf16(
                    af[m], bfr[n], acc[m][n], 0, 0, 0);
        __syncthreads();
    }

    // epilogue: D[row=(lane>>4)*4+r][col=lane&15]
    #pragma unroll
    for (int n = 0; n < WN; ++n) {
        int gcol = col0 + (wn * WN + n) * 16 + frow;
        float bv = bias[gcol];
        if constexpr (MODE == 0) {
            int b = gcol >> 8, c = gcol & 255;
            ushort* dst = (b == 0) ? (ushort*)C0 : (b == 1) ? (ushort*)C1 : (ushort*)C2;
            #pragma unroll
            for (int m = 0; m < WM; ++m) {
                int grow0 = row0 + (wm * WM + m) * 16 + fg * 4;
                #pragma unroll
                for (int r = 0; r < 4; ++r)
                    dst[(size_t)(grow0 + r) * 256 + c] = f2bf(acc[m][n][r] + bv);
            }
        } else {
            float* dst = (float*)C0;
            #pragma unroll
            for (int m = 0; m < WM; ++m) {
                int grow0 = row0 + (wm * WM + m) * 16 + fg * 4;
                #pragma unroll
                for (int r = 0; r < 4; ++r)
                    dst[(size_t)(grow0 + r) * N + gcol] = acc[m][n][r] + bv;
            }
        }
    }
}

// ---------------------------------------------------------------------------
// Fused relational attention, NO bias LDS staging.
// One block per (bt, i); 256 threads; LDS = 1 KB (p only) -> 8 blocks/CU.
// Scores phase streams the 32 KB bias slab from HBM (coalesced 16B/lane);
// PV phase re-reads it column-wise from L2 (256 B contiguous per wave).
// ---------------------------------------------------------------------------
__global__ __launch_bounds__(256) void relattn_kernel(
    const ushort* __restrict__ qb, const ushort* __restrict__ kb,
    const ushort* __restrict__ vb, const float* __restrict__ bias,
    const int* __restrict__ mask, ushort* __restrict__ attn_out)
{
    __shared__ float p_lds[256];

    const int blk = blockIdx.x;       // bt*32 + i
    const int bt = blk >> 5;
    const int tid = threadIdx.x;
    const int j = tid & 31, h = tid >> 5;

    // ---- scores: thread = (h, j) ----
    const ushort* qrow = qb + (size_t)blk * 256 + h * 32;
    const ushort* krow = kb + (size_t)(bt * 32 + j) * 256 + h * 32;
    const float*  brow = bias + (size_t)blk * 8192 + j * 256 + h * 32;

    float s = 0.f;
    #pragma unroll
    for (int it = 0; it < 4; ++it) {
        bf16x8 q8 = *(const bf16x8*)(qrow + it * 8);
        bf16x8 k8 = *(const bf16x8*)(krow + it * 8);
        float4 b0 = *(const float4*)(brow + it * 8);
        float4 b1 = *(const float4*)(brow + it * 8 + 4);
        s += bf2f((ushort)q8[0]) * (bf2f((ushort)k8[0]) + b0.x)
           + bf2f((ushort)q8[1]) * (bf2f((ushort)k8[1]) + b0.y)
           + bf2f((ushort)q8[2]) * (bf2f((ushort)k8[2]) + b0.z)
           + bf2f((ushort)q8[3]) * (bf2f((ushort)k8[3]) + b0.w)
           + bf2f((ushort)q8[4]) * (bf2f((ushort)k8[4]) + b1.x)
           + bf2f((ushort)q8[5]) * (bf2f((ushort)k8[5]) + b1.y)
           + bf2f((ushort)q8[6]) * (bf2f((ushort)k8[6]) + b1.z)
           + bf2f((ushort)q8[7]) * (bf2f((ushort)k8[7]) + b1.w);
    }
    s *= 0.17677669529663687f;  // 1/sqrt(32)

    const bool alive = (mask[bt * 32 + j] != 0);
    s = alive ? s : -__builtin_inff();

    float m = s;
    #pragma unroll
    for (int off = 16; off; off >>= 1) m = fmaxf(m, __shfl_xor(m, off));
    const bool dead = (m == -__builtin_inff());
    float p = alive ? __expf(s - m) : 0.f;
    float l = p;
    #pragma unroll
    for (int off = 16; off; off >>= 1) l += __shfl_xor(l, off);
    p_lds[tid] = dead ? 0.f : p / l;
    __syncthreads();

    // ---- PV: thread = (h2, d); col index == tid ----
    const ushort* vcol = vb + (size_t)bt * 8192 + tid;
    const float*  bcol = bias + (size_t)blk * 8192 + tid;
    const int hbase = tid & 0xE0;
    float o = 0.f;
    #pragma unroll
    for (int jj = 0; jj < 32; ++jj) {
        float pv = p_lds[hbase | jj];
        float vv = bf2f(vcol[(size_t)jj * 256]);
        float bb = bcol[(size_t)jj * 256];
        o += pv * (vv + bb);
    }
    attn_out[(size_t)blk * 256 + tid] = f2bf(o);
}

extern "C" void kernel_launch(void* const* d_in, const int* in_sizes, int n_in,
                              void* d_out, int out_size, void* d_ws, size_t ws_size,
                              hipStream_t stream) {
    const float* x      = (const float*)d_in[0];   // (4096,256)
    const float* bias_f = (const float*)d_in[1];   // (4096,32,256)
    const int*   mask   = (const int*)d_in[2];     // (4096,)
    const float* w_qkv  = (const float*)d_in[3];   // (256,768)
    const float* b_qkv  = (const float*)d_in[4];   // (768,)
    const float* w_proj = (const float*)d_in[5];   // (256,256)
    const float* b_proj = (const float*)d_in[6];   // (256,)
    float* out = (float*)d_out;                    // (4096,256)

    // workspace: q,k,v,attn_out each 4096*256 bf16 (2 MB) = 8.4 MB total
    ushort* qb = (ushort*)d_ws;
    ushort* kb = qb + (size_t)4096 * 256;
    ushort* vb = kb + (size_t)4096 * 256;
    ushort* ao = vb + (size_t)4096 * 256;

    // qkv = x @ w_qkv + b_qkv  ->  bf16 q/k/v   (M=4096, N=768, K=256)
    gemm_fused<64, 64, 2, 2, 0><<<dim3(12, 64), 256, 0, stream>>>(
        x, w_qkv, 768, b_qkv, qb, kb, vb, 256, 768);

    relattn_kernel<<<4096, 256, 0, stream>>>(qb, kb, vb, bias_f, mask, ao);

    // out = attn_out @ w_proj + b_proj   (M=4096, N=256, K=256)
    gemm_fused<32, 64, 1, 4, 1><<<dim3(4, 128), 256, 0, stream>>>(
        ao, w_proj, 256, b_proj, out, nullptr, nullptr, 256, 256);
}

// Round 5
// 58.333 us; speedup vs baseline: 1.3932x; 1.3932x over previous
//
#include <hip/hip_runtime.h>
#include <math.h>

typedef __attribute__((ext_vector_type(8))) short bf16x8;
typedef __attribute__((ext_vector_type(4))) short bf16x4;
typedef __attribute__((ext_vector_type(4))) float f32x4;

__device__ inline ushort f2bf(float f) {
    union { float f; uint u; } v; v.f = f;
    uint u = v.u;
    return (ushort)((u + 0x7fff + ((u >> 16) & 1)) >> 16);   // RNE
}
__device__ inline float bf2f(ushort u) {
    union { uint u; float f; } v; v.u = ((uint)u) << 16; return v.f;
}

// ---------------------------------------------------------------------------
// MFMA bf16 GEMM, converts inputs on the fly.  (unchanged from round 3)
//   A: MODE0 = f32 row-major (lda=K), MODE1 = bf16 row-major (lda=K)
//   B: f32 row-major (K x N, ldb), transposed+converted into LDS
//   out: MODE0 = bf16 split into 3 buffers of 256 cols (q,k,v); MODE1 = f32
// ---------------------------------------------------------------------------
template<int BM, int BN, int WGM, int WGN, int MODE>
__global__ __launch_bounds__(WGM * WGN * 64) void gemm_fused(
    const void* __restrict__ Ap, const float* __restrict__ Bw, int ldb,
    const float* __restrict__ bias,
    void* __restrict__ C0, void* __restrict__ C1, void* __restrict__ C2,
    int K, int N)
{
    constexpr int BK = 32;
    constexpr int NT = WGM * WGN * 64;
    constexpr int WM = BM / (WGM * 16);
    constexpr int WN = BN / (WGN * 16);

    __shared__ ushort As[BM * BK];
    __shared__ ushort Bs[BN * BK];

    const int tid = threadIdx.x;
    const int lane = tid & 63, wid = tid >> 6;
    const int wm = wid / WGN, wn = wid % WGN;
    const int row0 = blockIdx.y * BM, col0 = blockIdx.x * BN;
    const int frow = lane & 15, fg = lane >> 4;

    f32x4 acc[WM][WN] = {};

    for (int k0 = 0; k0 < K; k0 += BK) {
        if constexpr (MODE == 0) {
            #pragma unroll
            for (int ci = tid; ci < BM * 8; ci += NT) {
                int r = ci >> 3, kq = ci & 7, g = kq >> 1;
                float4 v = *(const float4*)((const float*)Ap + (size_t)(row0 + r) * K + k0 + kq * 4);
                bf16x4 o;
                o[0] = (short)f2bf(v.x); o[1] = (short)f2bf(v.y);
                o[2] = (short)f2bf(v.z); o[3] = (short)f2bf(v.w);
                *(bf16x4*)&As[r * 32 + ((g ^ ((r >> 1) & 3)) << 3) + (kq & 1) * 4] = o;
            }
        } else {
            #pragma unroll
            for (int ci = tid; ci < BM * 4; ci += NT) {
                int r = ci >> 2, g = ci & 3;
                bf16x8 v = *(const bf16x8*)((const ushort*)Ap + (size_t)(row0 + r) * K + k0 + g * 8);
                *(bf16x8*)&As[r * 32 + ((g ^ ((r >> 1) & 3)) << 3)] = v;
            }
        }
        #pragma unroll
        for (int ci = tid; ci < BN * 8; ci += NT) {
            int kk = ci & 31, n4 = ci >> 5;
            float4 v = *(const float4*)&Bw[(size_t)(k0 + kk) * ldb + col0 + n4 * 4];
            float vv[4] = {v.x, v.y, v.z, v.w};
            #pragma unroll
            for (int e = 0; e < 4; ++e) {
                int n = n4 * 4 + e;
                Bs[n * 32 + (((kk >> 3) ^ ((n >> 1) & 3)) << 3) + (kk & 7)] = f2bf(vv[e]);
            }
        }
        __syncthreads();

        bf16x8 af[WM], bfr[WN];
        #pragma unroll
        for (int m = 0; m < WM; ++m) {
            int r = (wm * WM + m) * 16 + frow;
            af[m] = *(const bf16x8*)&As[r * 32 + ((fg ^ ((r >> 1) & 3)) << 3)];
        }
        #pragma unroll
        for (int n = 0; n < WN; ++n) {
            int r = (wn * WN + n) * 16 + frow;
            bfr[n] = *(const bf16x8*)&Bs[r * 32 + ((fg ^ ((r >> 1) & 3)) << 3)];
        }
        #pragma unroll
        for (int m = 0; m < WM; ++m)
            #pragma unroll
            for (int n = 0; n < WN; ++n)
                acc[m][n] = __builtin_amdgcn_mfma_f32_16x16x32_bf16(
                    af[m], bfr[n], acc[m][n], 0, 0, 0);
        __syncthreads();
    }

    #pragma unroll
    for (int n = 0; n < WN; ++n) {
        int gcol = col0 + (wn * WN + n) * 16 + frow;
        float bv = bias[gcol];
        if constexpr (MODE == 0) {
            int b = gcol >> 8, c = gcol & 255;
            ushort* dst = (b == 0) ? (ushort*)C0 : (b == 1) ? (ushort*)C1 : (ushort*)C2;
            #pragma unroll
            for (int m = 0; m < WM; ++m) {
                int grow0 = row0 + (wm * WM + m) * 16 + fg * 4;
                #pragma unroll
                for (int r = 0; r < 4; ++r)
                    dst[(size_t)(grow0 + r) * 256 + c] = f2bf(acc[m][n][r] + bv);
            }
        } else {
            float* dst = (float*)C0;
            #pragma unroll
            for (int m = 0; m < WM; ++m) {
                int grow0 = row0 + (wm * WM + m) * 16 + fg * 4;
                #pragma unroll
                for (int r = 0; r < 4; ++r)
                    dst[(size_t)(grow0 + r) * N + gcol] = acc[m][n][r] + bv;
            }
        }
    }
}

// ---------------------------------------------------------------------------
// Fused relational attention: bias staged into LDS as BF16 (16 KB) ->
// 8 blocks/CU (vs 4 with f32 staging). Coalesced float4 HBM stream + RNE
// convert in registers + swizzled LDS writes.
// Swizzle: 16B chunk c of row j stored at chunk (c ^ (j&7)).
//   scores read: 4 lanes share (j&7,c) -> same-address broadcast, free.
//   PV read:     2B scalar, banks spread by permutation, <=2-way, free.
// ---------------------------------------------------------------------------
__global__ __launch_bounds__(256) void relattn_kernel(
    const ushort* __restrict__ qb, const ushort* __restrict__ kb,
    const ushort* __restrict__ vb, const float* __restrict__ bias,
    const int* __restrict__ mask, ushort* __restrict__ attn_out)
{
    __shared__ ushort bias_lds[8192];   // bf16, 32 rows x 256 cols, swizzled
    __shared__ float p_lds[256];

    const int blk = blockIdx.x;         // bt*32 + i
    const int bt = blk >> 5;
    const int tid = threadIdx.x;
    const float* bsrc = bias + (size_t)blk * 8192;

    // ---- stage: 8 x (coalesced float4 load -> 4x bf16 -> 8B LDS write) ----
    #pragma unroll
    for (int it = 0; it < 8; ++it) {
        int idx4 = it * 256 + tid;              // linear float4 index 0..2047
        float4 v = *(const float4*)(bsrc + (size_t)idx4 * 4);
        int j = idx4 >> 6;                      // bias row
        int c = (idx4 & 63) >> 1;               // 16B chunk within row
        int half = idx4 & 1;
        bf16x4 o;
        o[0] = (short)f2bf(v.x); o[1] = (short)f2bf(v.y);
        o[2] = (short)f2bf(v.z); o[3] = (short)f2bf(v.w);
        *(bf16x4*)&bias_lds[j * 256 + ((c ^ (j & 7)) << 3) + half * 4] = o;
    }
    __syncthreads();

    // ---- scores: thread = (h, j) ----
    const int j = tid & 31, h = tid >> 5;
    const ushort* qrow = qb + (size_t)blk * 256 + h * 32;
    const ushort* krow = kb + (size_t)(bt * 32 + j) * 256 + h * 32;

    float s = 0.f;
    #pragma unroll
    for (int it = 0; it < 4; ++it) {
        bf16x8 q8 = *(const bf16x8*)(qrow + it * 8);
        bf16x8 k8 = *(const bf16x8*)(krow + it * 8);
        int c = h * 4 + it;
        bf16x8 b8 = *(const bf16x8*)&bias_lds[j * 256 + ((c ^ (j & 7)) << 3)];
        #pragma unroll
        for (int e = 0; e < 8; ++e)
            s += bf2f((ushort)q8[e]) * (bf2f((ushort)k8[e]) + bf2f((ushort)b8[e]));
    }
    s *= 0.17677669529663687f;  // 1/sqrt(32)

    const bool alive = (mask[bt * 32 + j] != 0);
    s = alive ? s : -__builtin_inff();

    float m = s;
    #pragma unroll
    for (int off = 16; off; off >>= 1) m = fmaxf(m, __shfl_xor(m, off));
    const bool dead = (m == -__builtin_inff());
    float p = alive ? __expf(s - m) : 0.f;
    float l = p;
    #pragma unroll
    for (int off = 16; off; off >>= 1) l += __shfl_xor(l, off);
    p_lds[tid] = dead ? 0.f : p / l;
    __syncthreads();

    // ---- PV: thread = (h2, d); col index == tid ----
    const ushort* vcol = vb + (size_t)bt * 8192 + tid;
    const int hbase = tid & 0xE0;
    const int cc = tid >> 3, dlo = tid & 7;
    float o = 0.f;
    #pragma unroll
    for (int jj = 0; jj < 32; ++jj) {
        float pv = p_lds[hbase | jj];
        float vv = bf2f(vcol[(size_t)jj * 256]);
        float bb = bf2f(bias_lds[jj * 256 + ((cc ^ (jj & 7)) << 3) + dlo]);
        o += pv * (vv + bb);
    }
    attn_out[(size_t)blk * 256 + tid] = f2bf(o);
}

extern "C" void kernel_launch(void* const* d_in, const int* in_sizes, int n_in,
                              void* d_out, int out_size, void* d_ws, size_t ws_size,
                              hipStream_t stream) {
    const float* x      = (const float*)d_in[0];   // (4096,256)
    const float* bias_f = (const float*)d_in[1];   // (4096,32,256)
    const int*   mask   = (const int*)d_in[2];     // (4096,)
    const float* w_qkv  = (const float*)d_in[3];   // (256,768)
    const float* b_qkv  = (const float*)d_in[4];   // (768,)
    const float* w_proj = (const float*)d_in[5];   // (256,256)
    const float* b_proj = (const float*)d_in[6];   // (256,)
    float* out = (float*)d_out;                    // (4096,256)

    // workspace: q,k,v,attn_out each 4096*256 bf16 (2 MB) = 8.4 MB total
    ushort* qb = (ushort*)d_ws;
    ushort* kb = qb + (size_t)4096 * 256;
    ushort* vb = kb + (size_t)4096 * 256;
    ushort* ao = vb + (size_t)4096 * 256;

    // qkv = x @ w_qkv + b_qkv  ->  bf16 q/k/v   (M=4096, N=768, K=256)
    gemm_fused<64, 64, 2, 2, 0><<<dim3(12, 64), 256, 0, stream>>>(
        x, w_qkv, 768, b_qkv, qb, kb, vb, 256, 768);

    relattn_kernel<<<4096, 256, 0, stream>>>(qb, kb, vb, bias_f, mask, ao);

    // out = attn_out @ w_proj + b_proj   (M=4096, N=256, K=256)
    gemm_fused<32, 64, 1, 4, 1><<<dim3(4, 128), 256, 0, stream>>>(
        ao, w_proj, 256, b_proj, out, nullptr, nullptr, 256, 256);
}

// Round 6
// 57.989 us; speedup vs baseline: 1.4015x; 1.0059x over previous
//
#include <hip/hip_runtime.h>
#include <math.h>

typedef __attribute__((ext_vector_type(8))) short bf16x8;
typedef __attribute__((ext_vector_type(4))) short bf16x4;
typedef __attribute__((ext_vector_type(4))) float f32x4;

__device__ inline ushort f2bf(float f) {
    union { float f; uint u; } v; v.f = f;
    uint u = v.u;
    return (ushort)((u + 0x7fff + ((u >> 16) & 1)) >> 16);   // RNE
}
__device__ inline float bf2f(ushort u) {
    union { uint u; float f; } v; v.u = ((uint)u) << 16; return v.f;
}

// ---------------------------------------------------------------------------
// MFMA bf16 GEMM, converts inputs on the fly.  (unchanged from round 3/5)
// ---------------------------------------------------------------------------
template<int BM, int BN, int WGM, int WGN, int MODE>
__global__ __launch_bounds__(WGM * WGN * 64) void gemm_fused(
    const void* __restrict__ Ap, const float* __restrict__ Bw, int ldb,
    const float* __restrict__ bias,
    void* __restrict__ C0, void* __restrict__ C1, void* __restrict__ C2,
    int K, int N)
{
    constexpr int BK = 32;
    constexpr int NT = WGM * WGN * 64;
    constexpr int WM = BM / (WGM * 16);
    constexpr int WN = BN / (WGN * 16);

    __shared__ ushort As[BM * BK];
    __shared__ ushort Bs[BN * BK];

    const int tid = threadIdx.x;
    const int lane = tid & 63, wid = tid >> 6;
    const int wm = wid / WGN, wn = wid % WGN;
    const int row0 = blockIdx.y * BM, col0 = blockIdx.x * BN;
    const int frow = lane & 15, fg = lane >> 4;

    f32x4 acc[WM][WN] = {};

    for (int k0 = 0; k0 < K; k0 += BK) {
        if constexpr (MODE == 0) {
            #pragma unroll
            for (int ci = tid; ci < BM * 8; ci += NT) {
                int r = ci >> 3, kq = ci & 7, g = kq >> 1;
                float4 v = *(const float4*)((const float*)Ap + (size_t)(row0 + r) * K + k0 + kq * 4);
                bf16x4 o;
                o[0] = (short)f2bf(v.x); o[1] = (short)f2bf(v.y);
                o[2] = (short)f2bf(v.z); o[3] = (short)f2bf(v.w);
                *(bf16x4*)&As[r * 32 + ((g ^ ((r >> 1) & 3)) << 3) + (kq & 1) * 4] = o;
            }
        } else {
            #pragma unroll
            for (int ci = tid; ci < BM * 4; ci += NT) {
                int r = ci >> 2, g = ci & 3;
                bf16x8 v = *(const bf16x8*)((const ushort*)Ap + (size_t)(row0 + r) * K + k0 + g * 8);
                *(bf16x8*)&As[r * 32 + ((g ^ ((r >> 1) & 3)) << 3)] = v;
            }
        }
        #pragma unroll
        for (int ci = tid; ci < BN * 8; ci += NT) {
            int kk = ci & 31, n4 = ci >> 5;
            float4 v = *(const float4*)&Bw[(size_t)(k0 + kk) * ldb + col0 + n4 * 4];
            float vv[4] = {v.x, v.y, v.z, v.w};
            #pragma unroll
            for (int e = 0; e < 4; ++e) {
                int n = n4 * 4 + e;
                Bs[n * 32 + (((kk >> 3) ^ ((n >> 1) & 3)) << 3) + (kk & 7)] = f2bf(vv[e]);
            }
        }
        __syncthreads();

        bf16x8 af[WM], bfr[WN];
        #pragma unroll
        for (int m = 0; m < WM; ++m) {
            int r = (wm * WM + m) * 16 + frow;
            af[m] = *(const bf16x8*)&As[r * 32 + ((fg ^ ((r >> 1) & 3)) << 3)];
        }
        #pragma unroll
        for (int n = 0; n < WN; ++n) {
            int r = (wn * WN + n) * 16 + frow;
            bfr[n] = *(const bf16x8*)&Bs[r * 32 + ((fg ^ ((r >> 1) & 3)) << 3)];
        }
        #pragma unroll
        for (int m = 0; m < WM; ++m)
            #pragma unroll
            for (int n = 0; n < WN; ++n)
                acc[m][n] = __builtin_amdgcn_mfma_f32_16x16x32_bf16(
                    af[m], bfr[n], acc[m][n], 0, 0, 0);
        __syncthreads();
    }

    #pragma unroll
    for (int n = 0; n < WN; ++n) {
        int gcol = col0 + (wn * WN + n) * 16 + frow;
        float bv = bias[gcol];
        if constexpr (MODE == 0) {
            int b = gcol >> 8, c = gcol & 255;
            ushort* dst = (b == 0) ? (ushort*)C0 : (b == 1) ? (ushort*)C1 : (ushort*)C2;
            #pragma unroll
            for (int m = 0; m < WM; ++m) {
                int grow0 = row0 + (wm * WM + m) * 16 + fg * 4;
                #pragma unroll
                for (int r = 0; r < 4; ++r)
                    dst[(size_t)(grow0 + r) * 256 + c] = f2bf(acc[m][n][r] + bv);
            }
        } else {
            float* dst = (float*)C0;
            #pragma unroll
            for (int m = 0; m < WM; ++m) {
                int grow0 = row0 + (wm * WM + m) * 16 + fg * 4;
                #pragma unroll
                for (int r = 0; r < 4; ++r)
                    dst[(size_t)(grow0 + r) * N + gcol] = acc[m][n][r] + bv;
            }
        }
    }
}

// ---------------------------------------------------------------------------
// Wave-autonomous relational attention: NO __syncthreads anywhere.
// Block = (bt,i), 4 waves; wave w owns heads {2w, 2w+1} end-to-end:
//   - stages bias rows 0..31 x cols [w*64, w*64+64) as bf16 into its own
//     4 KB LDS quadrant (32 indep 256B-coalesced loads; same-wave write->read
//     needs only lgkmcnt -- no barrier)
//   - scores thread (h=2w+(L>>5), j=L&31); softmax via shfl_xor in 32-lane group
//   - p stays in registers; PV pulls p[h,jj] via __shfl from the same half-wave
// LDS chunk swizzle: 16B chunk cc of row j at slot cc^(j&7)
//   (stage write 2-way, scores b128 read 4-way, PV scalar 2-way -- all ~free)
// ---------------------------------------------------------------------------
__global__ __launch_bounds__(256) void relattn_kernel(
    const ushort* __restrict__ qb, const ushort* __restrict__ kb,
    const ushort* __restrict__ vb, const float* __restrict__ bias,
    const int* __restrict__ mask, ushort* __restrict__ attn_out)
{
    __shared__ ushort slab[4][32 * 64];   // per-wave bf16 col-slab, 4 KB each

    const int blk = blockIdx.x;           // bt*32 + i
    const int bt = blk >> 5;
    const int tid = threadIdx.x;
    const int w = tid >> 6, L = tid & 63;
    const int hw = L >> 5;                // which of the wave's two heads
    const int h = 2 * w + hw;
    const int jd = L & 31;                // j in scores, d in PV

    ushort* sl = slab[w];

    // ---- stage: wave's 8 KB f32 col-slab -> 4 KB bf16 LDS, batched 8-deep ----
    const float* bs = bias + (size_t)blk * 8192 + w * 64 + L;   // + j*256 per row
    #pragma unroll
    for (int g = 0; g < 4; ++g) {
        float t0 = bs[(size_t)(g * 8 + 0) * 256];
        float t1 = bs[(size_t)(g * 8 + 1) * 256];
        float t2 = bs[(size_t)(g * 8 + 2) * 256];
        float t3 = bs[(size_t)(g * 8 + 3) * 256];
        float t4 = bs[(size_t)(g * 8 + 4) * 256];
        float t5 = bs[(size_t)(g * 8 + 5) * 256];
        float t6 = bs[(size_t)(g * 8 + 6) * 256];
        float t7 = bs[(size_t)(g * 8 + 7) * 256];
        float tt[8] = {t0, t1, t2, t3, t4, t5, t6, t7};
        #pragma unroll
        for (int r = 0; r < 8; ++r) {
            int j = g * 8 + r;
            sl[j * 64 + ((((L >> 3) ^ (j & 7)) << 3) | (L & 7))] = f2bf(tt[r]);
        }
    }

    // ---- scores: thread (h, j=jd) ----
    const ushort* qrow = qb + (size_t)blk * 256 + h * 32;
    const ushort* krow = kb + (size_t)(bt * 32 + jd) * 256 + h * 32;
    float s = 0.f;
    #pragma unroll
    for (int t = 0; t < 4; ++t) {
        bf16x8 q8 = *(const bf16x8*)(qrow + t * 8);
        bf16x8 k8 = *(const bf16x8*)(krow + t * 8);
        int cc = hw * 4 + t;
        bf16x8 b8 = *(const bf16x8*)&sl[jd * 64 + ((cc ^ (jd & 7)) << 3)];
        #pragma unroll
        for (int e = 0; e < 8; ++e)
            s += bf2f((ushort)q8[e]) * (bf2f((ushort)k8[e]) + bf2f((ushort)b8[e]));
    }
    s *= 0.17677669529663687f;  // 1/sqrt(32)

    const bool alive = (mask[bt * 32 + jd] != 0);
    s = alive ? s : -__builtin_inff();

    // softmax across the 32-lane j-group (xor masks 1..16 stay in-group)
    float m = s;
    #pragma unroll
    for (int off = 16; off; off >>= 1) m = fmaxf(m, __shfl_xor(m, off));
    const bool dead = (m == -__builtin_inff());
    float p = alive ? __expf(s - m) : 0.f;
    float l = p;
    #pragma unroll
    for (int off = 16; off; off >>= 1) l += __shfl_xor(l, off);
    float pn = dead ? 0.f : p / l;

    // ---- PV: thread (h, d=jd); p pulled via shfl from same half-wave ----
    const ushort* vcol = vb + (size_t)bt * 8192 + w * 64 + L;   // + j*256 per row
    const int half = L & 32;
    float o0 = 0.f, o1 = 0.f, o2 = 0.f, o3 = 0.f;
    #pragma unroll
    for (int jq = 0; jq < 8; ++jq) {
        int j0 = jq * 4;
        float pa = __shfl(pn, half | (j0 + 0));
        float pb = __shfl(pn, half | (j0 + 1));
        float pc = __shfl(pn, half | (j0 + 2));
        float pd = __shfl(pn, half | (j0 + 3));
        float va = bf2f(vcol[(size_t)(j0 + 0) * 256]);
        float vbv = bf2f(vcol[(size_t)(j0 + 1) * 256]);
        float vc = bf2f(vcol[(size_t)(j0 + 2) * 256]);
        float vd = bf2f(vcol[(size_t)(j0 + 3) * 256]);
        float ba = bf2f(sl[(j0 + 0) * 64 + ((((L >> 3) ^ ((j0 + 0) & 7)) << 3) | (L & 7))]);
        float bb = bf2f(sl[(j0 + 1) * 64 + ((((L >> 3) ^ ((j0 + 1) & 7)) << 3) | (L & 7))]);
        float bc = bf2f(sl[(j0 + 2) * 64 + ((((L >> 3) ^ ((j0 + 2) & 7)) << 3) | (L & 7))]);
        float bd = bf2f(sl[(j0 + 3) * 64 + ((((L >> 3) ^ ((j0 + 3) & 7)) << 3) | (L & 7))]);
        o0 += pa * (va + ba);
        o1 += pb * (vbv + bb);
        o2 += pc * (vc + bc);
        o3 += pd * (vd + bd);
    }
    attn_out[(size_t)blk * 256 + w * 64 + L] = f2bf((o0 + o1) + (o2 + o3));
}

extern "C" void kernel_launch(void* const* d_in, const int* in_sizes, int n_in,
                              void* d_out, int out_size, void* d_ws, size_t ws_size,
                              hipStream_t stream) {
    const float* x      = (const float*)d_in[0];   // (4096,256)
    const float* bias_f = (const float*)d_in[1];   // (4096,32,256)
    const int*   mask   = (const int*)d_in[2];     // (4096,)
    const float* w_qkv  = (const float*)d_in[3];   // (256,768)
    const float* b_qkv  = (const float*)d_in[4];   // (768,)
    const float* w_proj = (const float*)d_in[5];   // (256,256)
    const float* b_proj = (const float*)d_in[6];   // (256,)
    float* out = (float*)d_out;                    // (4096,256)

    // workspace: q,k,v,attn_out each 4096*256 bf16 (2 MB) = 8.4 MB total
    ushort* qb = (ushort*)d_ws;
    ushort* kb = qb + (size_t)4096 * 256;
    ushort* vb = kb + (size_t)4096 * 256;
    ushort* ao = vb + (size_t)4096 * 256;

    // qkv = x @ w_qkv + b_qkv  ->  bf16 q/k/v   (M=4096, N=768, K=256)
    gemm_fused<64, 64, 2, 2, 0><<<dim3(12, 64), 256, 0, stream>>>(
        x, w_qkv, 768, b_qkv, qb, kb, vb, 256, 768);

    relattn_kernel<<<4096, 256, 0, stream>>>(qb, kb, vb, bias_f, mask, ao);

    // out = attn_out @ w_proj + b_proj   (M=4096, N=256, K=256)
    gemm_fused<32, 64, 1, 4, 1><<<dim3(4, 128), 256, 0, stream>>>(
        ao, w_proj, 256, b_proj, out, nullptr, nullptr, 256, 256);
}